// Round 8
// baseline (671.772 us; speedup 1.0000x reference)
//
#include <hip/hip_runtime.h>
#include <hip/hip_bf16.h>
#include <stdint.h>

typedef __attribute__((ext_vector_type(8))) short short8;
typedef __attribute__((ext_vector_type(4))) float f32x4;
typedef unsigned int u32x4a __attribute__((vector_size(16)));             // 16B aligned
typedef unsigned int u32x4u __attribute__((vector_size(16), aligned(4))); // 4B aligned

__device__ inline unsigned short f2bf(float f) {
    union { float f; uint32_t u; } v; v.f = f;
    uint32_t u = v.u;
    uint32_t r = (u + 0x7FFFu + ((u >> 16) & 1u)) >> 16;
    return (unsigned short)r;
}

// async global->LDS, 16B per lane
__device__ inline void gl_lds16(const unsigned short* g, unsigned short* l) {
    __builtin_amdgcn_global_load_lds(
        (const uint32_t __attribute__((address_space(1)))*)(const void*)g,
        (uint32_t __attribute__((address_space(3)))*)(void*)l, 16, 0, 0);
}

// ---------------- weight converts ----------------
__global__ void cvt_w1(const float* __restrict__ w, unsigned short* __restrict__ A1) {
    int idx = blockIdx.x * 256 + threadIdx.x;   // 65536 total
    int row = idx >> 8, k = idx & 255;
    float v = (k < 243) ? w[row * 243 + k] : 0.f;
    A1[idx] = f2bf(v);
}

// conv2 weights, 256-row chunk tiles, XOR-swizzled:
// A2c[chunk 0..323][row 0..255][sw 0..7][j 0..7]
//   koct = sw ^ (row&7); kk = chunk*64 + koct*8 + j
// reordered-k: kk<18432: ic=kk/72, ky=(kk%72)>>3, kx=kk&7;  else kx=8 tail.
__global__ void cvt_w2(const float* __restrict__ w, unsigned short* __restrict__ A2c) {
    int idx = blockIdx.x * 256 + threadIdx.x;   // 5,308,416 total
    int j = idx & 7;
    int sw = (idx >> 3) & 7;
    int row = (idx >> 6) & 255;
    int chunk = idx >> 14;                      // 0..323
    int koct = sw ^ (row & 7);
    int kk = chunk * 64 + koct * 8 + j;
    int ic, ky, kx;
    if (kk < 18432) { ic = kk / 72; int rem = kk - ic * 72; ky = rem >> 3; kx = rem & 7; }
    else { int j2 = kk - 18432; ic = j2 / 9; ky = j2 - ic * 9; kx = 8; }
    A2c[idx] = f2bf(w[((row * 256 + ic) * 9 + ky) * 9 + kx]);
}

// ---------------- conv1 as implicit GEMM ----------------
__global__ __launch_bounds__(256) void conv1_gemm(
    const unsigned short* __restrict__ A,   // [256][256] bf16
    const float* __restrict__ x,            // [32][3][64][64]
    const float* __restrict__ bias,         // [256]
    unsigned short* __restrict__ h1)        // [32][256][56][56] bf16
{
    __shared__ __align__(16) unsigned short As[128 * 40];
    __shared__ __align__(16) unsigned short Bs[128 * 40];
    const int tid = threadIdx.x;
    const int m0 = blockIdx.y * 128;
    const int sx = (blockIdx.x & 7) * 98 + (blockIdx.x >> 3);
    const int n0 = sx * 128;
    const int lane = tid & 63;
    const int wave = tid >> 6;
    const int wy = wave & 1, wx = wave >> 1;
    const int l16 = lane & 15, q = lane >> 4;

    const int kp = tid & 15;
    const int gn = tid >> 4;
    int baseN[8];
#pragma unroll
    for (int j = 0; j < 8; ++j) {
        int n = n0 + gn * 8 + j;
        int b = n / 3136, p = n % 3136;
        int oy = p / 56, ox = p % 56;
        baseN[j] = b * 12288 + oy * 64 + ox;
    }

    f32x4 acc[4][4];
#pragma unroll
    for (int im = 0; im < 4; ++im)
#pragma unroll
        for (int in = 0; in < 4; ++in)
            acc[im][in] = (f32x4){0.f, 0.f, 0.f, 0.f};

    for (int k0 = 0; k0 < 256; k0 += 32) {
        __syncthreads();
#pragma unroll
        for (int s = 0; s < 2; ++s) {
            int slot = tid + s * 256;
            int row = slot >> 2, seg = slot & 3;
            u32x4a v = *(const u32x4a*)(A + (m0 + row) * 256 + k0 + seg * 8);
            *(u32x4a*)(&As[row * 40 + seg * 8]) = v;
        }
        int ka = k0 + 2 * kp, kb = ka + 1;
        int offa = 0, offb = 0;
        bool va = ka < 243, vb = kb < 243;
        if (va) { int c = ka / 81, t = ka % 81, ky = t / 9, kx = t % 9; offa = c * 4096 + ky * 64 + kx; }
        if (vb) { int c = kb / 81, t = kb % 81, ky = t / 9, kx = t % 9; offb = c * 4096 + ky * 64 + kx; }
#pragma unroll
        for (int j = 0; j < 8; ++j) {
            unsigned int ba = va ? (unsigned int)f2bf(x[baseN[j] + offa]) : 0u;
            unsigned int bb = vb ? (unsigned int)f2bf(x[baseN[j] + offb]) : 0u;
            *(unsigned int*)(&Bs[(gn * 8 + j) * 40 + 2 * kp]) = ba | (bb << 16);
        }
        __syncthreads();

        short8 af[4], bf[4];
#pragma unroll
        for (int im = 0; im < 4; ++im)
            af[im] = *(const short8*)(&As[(wy * 64 + im * 16 + l16) * 40 + q * 8]);
#pragma unroll
        for (int in = 0; in < 4; ++in)
            bf[in] = *(const short8*)(&Bs[(wx * 64 + in * 16 + l16) * 40 + q * 8]);
#pragma unroll
        for (int im = 0; im < 4; ++im)
#pragma unroll
            for (int in = 0; in < 4; ++in)
                acc[im][in] = __builtin_amdgcn_mfma_f32_16x16x32_bf16(af[im], bf[in], acc[im][in], 0, 0, 0);
    }

#pragma unroll
    for (int in = 0; in < 4; ++in) {
        int n = n0 + wx * 64 + in * 16 + l16;
        int b = n / 3136, p = n % 3136;
        int oy = p / 56, ox = p % 56;
#pragma unroll
        for (int im = 0; im < 4; ++im) {
#pragma unroll
            for (int r = 0; r < 4; ++r) {
                int oc = m0 + wy * 64 + im * 16 + q * 4 + r;
                float v = acc[im][in][r] + bias[oc];
                v = v > 0.f ? v : 0.f;
                h1[((b * 256 + oc) * 56 + oy) * 56 + ox] = f2bf(v);
            }
        }
    }
}

// ---------------- conv2: 256x256 big-tile implicit GEMM, contiguous split-K x18 ----------------
// BM=256 (full M, y-split merged) x BN=256, BK=64, 512 threads, 8 waves (2M x 4N),
// per-wave 128x64 (acc 128 AGPR). A via global_load_lds from pre-swizzled A2c
// (double-buffered); B reg-staged T14-style: load at chunk top, ds_write after
// compute, one __syncthreads per chunk. z<16: main K (kx 0..7, 16B-contiguous);
// z in {16,17}: kx=8 tail via per-slot gather (uniform 18 chunks per block).
__global__ __launch_bounds__(512, 2) void conv2_gemm(
    const unsigned short* __restrict__ A2c,  // [324][256][8][8] bf16 swizzled
    const unsigned short* __restrict__ h1,   // [32][256][56][56] bf16
    float* __restrict__ c2)                  // [32][256][576] fp32 (pre-zeroed)
{
    extern __shared__ __align__(16) unsigned short lds[];
    unsigned short* AsB = lds;           // 2 x 16384 u16 (64KB)
    unsigned short* BsB = lds + 32768;   // 2 x 16384 u16 (64KB)
    const int tid = threadIdx.x;
    const int sx = (blockIdx.x & 7) * 9 + (blockIdx.x >> 3);   // 72 = 8*9, XCD-chunked
    const int n0 = sx * 256;
    const int z = blockIdx.z;            // 0..17
    const int lane = tid & 63;
    const int wave = tid >> 6;           // 0..7
    const int wy = wave >> 2;            // 0..1 : m-half (128 rows)
    const int wx = wave & 3;             // 0..3 : n-quarter (64 cols)
    const int l16 = lane & 15, q = lane >> 4;

    // fragment LDS offsets (u16 units), XOR-swizzled
    int aoffA[8][2];
#pragma unroll
    for (int im = 0; im < 8; ++im)
#pragma unroll
        for (int h = 0; h < 2; ++h) {
            int row = wy * 128 + im * 16 + l16;
            aoffA[im][h] = (row * 8 + ((h * 4 + q) ^ (row & 7))) * 8;
        }
    int boffL[4][2];
#pragma unroll
    for (int in = 0; in < 4; ++in)
#pragma unroll
        for (int h = 0; h < 2; ++h) {
            int n = wx * 64 + in * 16 + l16;
            boffL[in][h] = (n * 8 + ((h * 4 + q) ^ (n & 7))) * 8;
        }

    // B staging source geometry: slot s = (wave*4+i)*64+lane; n = s>>3, sw = s&7
    const int sn = lane >> 3;                 // = n&7
    const int koctS = (lane & 7) ^ sn;        // lane-only koct
    int bsrc[4];
#pragma unroll
    for (int i = 0; i < 4; ++i) {
        int n = (wave * 4 + i) * 8 + sn;
        int ng = n0 + n;
        int b = ng / 576, p = ng % 576;
        int oy = p / 24, ox = p % 24;
        bsrc[i] = b * 802816 + (2 * oy) * 56 + 2 * ox;
    }

    f32x4 acc[8][4];
#pragma unroll
    for (int im = 0; im < 8; ++im)
#pragma unroll
        for (int in = 0; in < 4; ++in)
            acc[im][in] = (f32x4){0.f, 0.f, 0.f, 0.f};

    auto issueA = [&](int c, unsigned short* dst) {
        const unsigned short* at = A2c + (size_t)c * 16384;
#pragma unroll
        for (int i = 0; i < 4; ++i) {
            int sl = (wave * 4 + i) * 64 + lane;
            gl_lds16(at + sl * 8, dst + sl * 8);
        }
    };
    auto bloadMain = [&](int c, short8 (&R)[4]) {
        int octk = c * 8 + koctS;
        int ic = octk / 9, ky = octk - 9 * ic;
        int koff = ic * 3136 + ky * 56;
#pragma unroll
        for (int i = 0; i < 4; ++i) {
            u32x4u v = *(const u32x4u*)(h1 + bsrc[i] + koff);
            R[i] = __builtin_bit_cast(short8, v);
        }
    };
    auto bwriteMain = [&](short8 (&R)[4], unsigned short* dst) {
#pragma unroll
        for (int i = 0; i < 4; ++i) {
            int sl = (wave * 4 + i) * 64 + lane;
            *(short8*)(dst + sl * 8) = R[i];
        }
    };
    auto computeChunk = [&](const unsigned short* Ab, const unsigned short* Bb) {
        short8 bf[4][2];
#pragma unroll
        for (int in = 0; in < 4; ++in)
#pragma unroll
            for (int h = 0; h < 2; ++h)
                bf[in][h] = *(const short8*)(Bb + boffL[in][h]);
#pragma unroll
        for (int im = 0; im < 8; ++im) {
            short8 a0 = *(const short8*)(Ab + aoffA[im][0]);
            short8 a1 = *(const short8*)(Ab + aoffA[im][1]);
            __builtin_amdgcn_s_setprio(1);
#pragma unroll
            for (int in = 0; in < 4; ++in) {
                acc[im][in] = __builtin_amdgcn_mfma_f32_16x16x32_bf16(a0, bf[in][0], acc[im][in], 0, 0, 0);
                acc[im][in] = __builtin_amdgcn_mfma_f32_16x16x32_bf16(a1, bf[in][1], acc[im][in], 0, 0, 0);
            }
            __builtin_amdgcn_s_setprio(0);
        }
    };

    short8 R[4];

    if (z < 16) {
        const int c0 = z * 18;
        bloadMain(c0, R);
        issueA(c0, AsB);
        bwriteMain(R, BsB);
        __syncthreads();
        for (int t = 0; t < 18; ++t) {
            const int p = t & 1;
            unsigned short* Ap = AsB + p * 16384;
            unsigned short* Bp = BsB + p * 16384;
            unsigned short* An = AsB + (p ^ 1) * 16384;
            unsigned short* Bn = BsB + (p ^ 1) * 16384;
            if (t < 17) { bloadMain(c0 + t + 1, R); issueA(c0 + t + 1, An); }
            computeChunk(Ap, Bp);
            if (t < 17) bwriteMain(R, Bn);
            __syncthreads();
        }
    } else {
        // tail: kx = 8 column, per-slot gather. slots s = tid*4+k.
        const int c0 = 288 + (z - 16) * 18;
        int tb[4], kbase[4];
#pragma unroll
        for (int k = 0; k < 4; ++k) {
            int s = tid * 4 + k;
            int n = s >> 3, sw = s & 7;
            int koct = sw ^ (n & 7);
            int ng = n0 + n;
            int b = ng / 576, pp = ng % 576;
            int oy = pp / 24, ox = pp % 24;
            tb[k] = b * 802816 + (2 * oy) * 56 + 2 * ox + 8;
            kbase[k] = koct * 8;
        }
        auto bloadTail = [&](int c, short8 (&T)[4]) {
#pragma unroll
            for (int k = 0; k < 4; ++k) {
                int ob = c * 64 + kbase[k] - 18432;
                short8 v;
#pragma unroll
                for (int j = 0; j < 8; ++j) {
                    int j2 = ob + j;
                    int ic = j2 / 9, ky = j2 - 9 * ic;
                    v[j] = (short)h1[tb[k] + ic * 3136 + ky * 56];
                }
                T[k] = v;
            }
        };
        auto bwriteTail = [&](short8 (&T)[4], unsigned short* dst) {
#pragma unroll
            for (int k = 0; k < 4; ++k)
                *(short8*)(dst + (tid * 4 + k) * 8) = T[k];
        };
        bloadTail(c0, R);
        issueA(c0, AsB);
        bwriteTail(R, BsB);
        __syncthreads();
        for (int t = 0; t < 18; ++t) {
            const int p = t & 1;
            unsigned short* Ap = AsB + p * 16384;
            unsigned short* Bp = BsB + p * 16384;
            unsigned short* An = AsB + (p ^ 1) * 16384;
            unsigned short* Bn = BsB + (p ^ 1) * 16384;
            if (t < 17) { bloadTail(c0 + t + 1, R); issueA(c0 + t + 1, An); }
            computeChunk(Ap, Bp);
            if (t < 17) bwriteTail(R, Bn);
            __syncthreads();
        }
    }

    // epilogue: accumulate split-K partial into c2
#pragma unroll
    for (int in = 0; in < 4; ++in) {
        int nn = n0 + wx * 64 + in * 16 + l16;
        int bb = nn / 576, pp = nn % 576;
#pragma unroll
        for (int im = 0; im < 8; ++im) {
#pragma unroll
            for (int r = 0; r < 4; ++r) {
                int oc = wy * 128 + im * 16 + q * 4 + r;
                atomicAdd(&c2[(bb * 256 + oc) * 576 + pp], acc[im][in][r]);
            }
        }
    }
}

// ---------------- squash primary caps (+ conv2 bias) ----------------
__global__ void squash_caps(const float* __restrict__ c2, const float* __restrict__ bias,
                            float* __restrict__ caps) {
    int idx = blockIdx.x * 256 + threadIdx.x;   // 589824 = 32*32*576
    int b = idx / 18432;
    int rp = idx % 18432;
    int r = rp / 576, p = rp % 576;
    float s[8]; float n2 = 0.f;
#pragma unroll
    for (int d = 0; d < 8; ++d) {
        s[d] = c2[(b * 256 + r * 8 + d) * 576 + p] + bias[r * 8 + d];
        n2 += s[d] * s[d];
    }
    float sc = (n2 / (1.f + n2)) / sqrtf(n2 + 1e-8f);
#pragma unroll
    for (int d = 0; d < 8; ++d)
        caps[idx * 8 + d] = sc * s[d];
}

// ---------------- routing ----------------
__global__ __launch_bounds__(64) void capsum0(const float* __restrict__ caps,
                                              float* __restrict__ G) {
    int r = blockIdx.x, b = blockIdx.y;
    const float* cp = caps + (size_t)(b * 32 + r) * 4608;
    int tid = threadIdx.x;
    f32x4 s0 = (f32x4){0.f, 0.f, 0.f, 0.f}, s1 = s0;
    for (int jv = 0; jv < 9; ++jv) {
        const f32x4* qp = (const f32x4*)(cp + (jv * 64 + tid) * 8);
        s0 += qp[0]; s1 += qp[1];
    }
#pragma unroll
    for (int off = 32; off > 0; off >>= 1) {
#pragma unroll
        for (int k = 0; k < 4; ++k) {
            s0[k] += __shfl_down(s0[k], off, 64);
            s1[k] += __shfl_down(s1[k], off, 64);
        }
    }
    if (tid == 0) {
        float g[8] = {s0[0], s0[1], s0[2], s0[3], s1[0], s1[1], s1[2], s1[3]};
        float* gp = G + (size_t)((b * 32 + r) * 10) * 8;
        for (int cc = 0; cc < 10; ++cc)
#pragma unroll
            for (int ii = 0; ii < 8; ++ii) gp[cc * 8 + ii] = g[ii] * 0.1f;
    }
}

__global__ __launch_bounds__(64) void route_accum(const float* __restrict__ caps,
                                                  const float* __restrict__ W,
                                                  const float* __restrict__ V,
                                                  float* __restrict__ G) {
    int r = blockIdx.x, b = blockIdx.y;
    __shared__ float wv[80];
    __shared__ float red[80][64];
    int tid = threadIdx.x;
    for (int v = tid; v < 80; v += 64) {
        int cc = v >> 3, ii = v & 7;
        float s = 0.f;
#pragma unroll
        for (int o = 0; o < 16; ++o)
            s += W[((r * 10 + cc) * 8 + ii) * 16 + o] * V[(b * 10 + cc) * 16 + o];
        wv[v] = s;
    }
    __syncthreads();
    float g[80];
#pragma unroll
    for (int v = 0; v < 80; ++v) g[v] = 0.f;
    const float* cp = caps + (size_t)(b * 32 + r) * 4608;
    for (int j = 0; j < 9; ++j) {
        int p = j * 64 + tid;
        const f32x4* qp = (const f32x4*)(cp + p * 8);
        f32x4 c0 = qp[0], c1 = qp[1];
        float c8[8];
#pragma unroll
        for (int i = 0; i < 4; ++i) { c8[i] = c0[i]; c8[4 + i] = c1[i]; }
        float a[10]; float m = -1e30f;
#pragma unroll
        for (int cc = 0; cc < 10; ++cc) {
            float t = 0.f;
#pragma unroll
            for (int i = 0; i < 8; ++i) t += c8[i] * wv[cc * 8 + i];
            a[cc] = t; m = fmaxf(m, t);
        }
        float sum = 0.f;
#pragma unroll
        for (int cc = 0; cc < 10; ++cc) { a[cc] = __expf(a[cc] - m); sum += a[cc]; }
        float inv = 1.f / sum;
#pragma unroll
        for (int cc = 0; cc < 10; ++cc) {
            float w = a[cc] * inv;
#pragma unroll
            for (int i = 0; i < 8; ++i) g[cc * 8 + i] += w * c8[i];
        }
    }
#pragma unroll
    for (int v = 0; v < 80; ++v) red[v][tid] = g[v];
    __syncthreads();
    for (int v = tid; v < 80; v += 64) {
        float s = 0.f;
        for (int t = 0; t < 64; ++t) s += red[v][t];
        G[(b * 32 + r) * 80 + v] = s;
    }
}

__global__ __launch_bounds__(160) void sv_kernel(const float* __restrict__ G,
                                                 const float* __restrict__ W,
                                                 float* __restrict__ V,
                                                 float* __restrict__ out, int last) {
    int b = blockIdx.x;
    int c = threadIdx.x / 16, o = threadIdx.x % 16;
    __shared__ float sL[10][16];
    float s = 0.f;
    for (int r = 0; r < 32; ++r) {
        const float* g = G + ((b * 32 + r) * 10 + c) * 8;
        const float* w = W + ((r * 10 + c) * 8) * 16 + o;
#pragma unroll
        for (int i = 0; i < 8; ++i) s += g[i] * w[i * 16];
    }
    sL[c][o] = s;
    __syncthreads();
    float n2 = 0.f;
#pragma unroll
    for (int oo = 0; oo < 16; ++oo) { float t = sL[c][oo]; n2 += t * t; }
    float sc = (n2 / (1.f + n2)) / sqrtf(n2 + 1e-8f);
    float v = sc * s;
    V[(b * 10 + c) * 16 + o] += v;
    if (last) out[(b * 10 + c) * 16 + o] = v;
}

// ---------------- launch ----------------
extern "C" void kernel_launch(void* const* d_in, const int* in_sizes, int n_in,
                              void* d_out, int out_size, void* d_ws, size_t ws_size,
                              hipStream_t stream) {
    const float* x  = (const float*)d_in[0];
    const float* w1 = (const float*)d_in[1];
    const float* b1 = (const float*)d_in[2];
    const float* w2 = (const float*)d_in[3];
    const float* b2 = (const float*)d_in[4];
    const float* rw = (const float*)d_in[5];

    char* ws = (char*)d_ws;
    unsigned short* A1   = (unsigned short*)(ws);                  // 262,144 B
    unsigned short* A2   = (unsigned short*)(ws + 262144);         // 10,616,832 B
    unsigned short* h1   = (unsigned short*)(ws + 10878976);       // 51,380,224 B
    float*          c2   = (float*)(ws + 62259200);                // 18,874,368 B
    float*          caps = (float*)(ws + 81133568);                // 18,874,368 B
    float*          V    = (float*)(ws + 100007936);               // 20,480 B
    float*          G    = (float*)(ws + 100028416);               // 327,680 B

    hipFuncSetAttribute((const void*)conv2_gemm,
                        hipFuncAttributeMaxDynamicSharedMemorySize, 131072);

    hipLaunchKernelGGL(cvt_w1, dim3(256), dim3(256), 0, stream, w1, A1);
    hipLaunchKernelGGL(cvt_w2, dim3(20736), dim3(256), 0, stream, w2, A2);
    hipMemsetAsync(c2, 0, 18874368, stream);
    hipLaunchKernelGGL(conv1_gemm, dim3(784, 2), dim3(256), 0, stream, A1, x, b1, h1);
    hipLaunchKernelGGL(conv2_gemm, dim3(72, 1, 18), dim3(512), 131072, stream, A2, h1, c2);
    hipLaunchKernelGGL(squash_caps, dim3(2304), dim3(256), 0, stream, c2, b2, caps);
    hipMemsetAsync(V, 0, 5120 * sizeof(float), stream);
    hipLaunchKernelGGL(capsum0, dim3(32, 32), dim3(64), 0, stream, caps, G);
    hipLaunchKernelGGL(sv_kernel, dim3(32), dim3(160), 0, stream, G, rw, V, (float*)d_out, 0);
    for (int it = 1; it < 3; ++it) {
        hipLaunchKernelGGL(route_accum, dim3(32, 32), dim3(64), 0, stream, caps, rw, V, G);
        hipLaunchKernelGGL(sv_kernel, dim3(32), dim3(160), 0, stream, G, rw, V,
                           (float*)d_out, it == 2 ? 1 : 0);
    }
}

// Round 10
// 473.160 us; speedup vs baseline: 1.4198x; 1.4198x over previous
//
#include <hip/hip_runtime.h>
#include <hip/hip_bf16.h>
#include <stdint.h>

typedef __attribute__((ext_vector_type(8))) short short8;
typedef __attribute__((ext_vector_type(4))) float f32x4;
typedef unsigned int u32x4a __attribute__((vector_size(16)));             // 16B aligned
typedef unsigned int u32x4u __attribute__((vector_size(16), aligned(4))); // 4B aligned

__device__ inline unsigned short f2bf(float f) {
    union { float f; uint32_t u; } v; v.f = f;
    uint32_t u = v.u;
    uint32_t r = (u + 0x7FFFu + ((u >> 16) & 1u)) >> 16;
    return (unsigned short)r;
}

// async global->LDS, 16B per lane
__device__ inline void gl_lds16(const unsigned short* g, unsigned short* l) {
    __builtin_amdgcn_global_load_lds(
        (const uint32_t __attribute__((address_space(1)))*)(const void*)g,
        (uint32_t __attribute__((address_space(3)))*)(void*)l, 16, 0, 0);
}

// ---------------- weight/input converts ----------------
__global__ void cvt_w1(const float* __restrict__ w, unsigned short* __restrict__ A1) {
    int idx = blockIdx.x * 256 + threadIdx.x;   // 65536 total
    int row = idx >> 8, k = idx & 255;
    float v = (k < 243) ? w[row * 243 + k] : 0.f;
    A1[idx] = f2bf(v);
}

// x (f32) -> bf16 once; conv1's B staging then loads u16 scalars (bit-identical values)
__global__ void cvt_xbf(const float* __restrict__ x, unsigned short* __restrict__ xb) {
    int idx = blockIdx.x * 256 + threadIdx.x;   // 393216 total
    xb[idx] = f2bf(x[idx]);
}

// conv2 weights pre-shuffled into per-(m-tile, K-chunk) 16KB tiles, XOR-swizzled (R3 exact)
__global__ void cvt_w2(const float* __restrict__ w, unsigned short* __restrict__ A2t) {
    int idx = blockIdx.x * 256 + threadIdx.x;   // 5308416 total
    int j = idx & 7;
    int off16 = (idx >> 3) & 1023;
    int tile = idx >> 13;                 // 0..647
    int tm = tile / 324, chunk = tile - tm * 324;
    int row = off16 >> 3, sw = off16 & 7;
    int koct = sw ^ (row & 7);
    int kk = chunk * 64 + koct * 8 + j;
    int oc = tm * 128 + row;
    int ic, ky, kx;
    if (kk < 18432) { ic = kk / 72; int rem = kk - ic * 72; ky = rem >> 3; kx = rem & 7; }
    else { int j2 = kk - 18432; ic = j2 / 9; ky = j2 - ic * 9; kx = 8; }
    A2t[idx] = f2bf(w[((oc * 256 + ic) * 9 + ky) * 9 + kx]);
}

// ---------------- conv1 as implicit GEMM (R3 exact, B-stage from bf16 xb) ----------------
__global__ __launch_bounds__(256) void conv1_gemm(
    const unsigned short* __restrict__ A,   // [256][256] bf16
    const unsigned short* __restrict__ xb,  // [32][3][64][64] bf16
    const float* __restrict__ bias,         // [256]
    unsigned short* __restrict__ h1)        // [32][256][56][56] bf16
{
    __shared__ __align__(16) unsigned short As[128 * 40];
    __shared__ __align__(16) unsigned short Bs[128 * 40];
    const int tid = threadIdx.x;
    const int m0 = blockIdx.y * 128;
    // XCD-chunked swizzle: 784 = 8 * 98
    const int sx = (blockIdx.x & 7) * 98 + (blockIdx.x >> 3);
    const int n0 = sx * 128;
    const int lane = tid & 63;
    const int wave = tid >> 6;
    const int wy = wave & 1, wx = wave >> 1;
    const int l16 = lane & 15, q = lane >> 4;

    const int kp = tid & 15;
    const int gn = tid >> 4;
    int baseN[8];
#pragma unroll
    for (int j = 0; j < 8; ++j) {
        int n = n0 + gn * 8 + j;
        int b = n / 3136, p = n % 3136;
        int oy = p / 56, ox = p % 56;
        baseN[j] = b * 12288 + oy * 64 + ox;
    }

    f32x4 acc[4][4];
#pragma unroll
    for (int im = 0; im < 4; ++im)
#pragma unroll
        for (int in = 0; in < 4; ++in)
            acc[im][in] = (f32x4){0.f, 0.f, 0.f, 0.f};

    for (int k0 = 0; k0 < 256; k0 += 32) {
        __syncthreads();
#pragma unroll
        for (int s = 0; s < 2; ++s) {
            int slot = tid + s * 256;
            int row = slot >> 2, seg = slot & 3;
            u32x4a v = *(const u32x4a*)(A + (m0 + row) * 256 + k0 + seg * 8);
            *(u32x4a*)(&As[row * 40 + seg * 8]) = v;
        }
        int ka = k0 + 2 * kp, kb = ka + 1;
        int offa = 0, offb = 0;
        bool va = ka < 243, vb = kb < 243;
        if (va) { int c = ka / 81, t = ka % 81, ky = t / 9, kx = t % 9; offa = c * 4096 + ky * 64 + kx; }
        if (vb) { int c = kb / 81, t = kb % 81, ky = t / 9, kx = t % 9; offb = c * 4096 + ky * 64 + kx; }
#pragma unroll
        for (int j = 0; j < 8; ++j) {
            unsigned int ba = va ? (unsigned int)xb[baseN[j] + offa] : 0u;
            unsigned int bb = vb ? (unsigned int)xb[baseN[j] + offb] : 0u;
            *(unsigned int*)(&Bs[(gn * 8 + j) * 40 + 2 * kp]) = ba | (bb << 16);
        }
        __syncthreads();

        short8 af[4], bf[4];
#pragma unroll
        for (int im = 0; im < 4; ++im)
            af[im] = *(const short8*)(&As[(wy * 64 + im * 16 + l16) * 40 + q * 8]);
#pragma unroll
        for (int in = 0; in < 4; ++in)
            bf[in] = *(const short8*)(&Bs[(wx * 64 + in * 16 + l16) * 40 + q * 8]);
#pragma unroll
        for (int im = 0; im < 4; ++im)
#pragma unroll
            for (int in = 0; in < 4; ++in)
                acc[im][in] = __builtin_amdgcn_mfma_f32_16x16x32_bf16(af[im], bf[in], acc[im][in], 0, 0, 0);
    }

#pragma unroll
    for (int in = 0; in < 4; ++in) {
        int n = n0 + wx * 64 + in * 16 + l16;
        int b = n / 3136, p = n % 3136;
        int oy = p / 56, ox = p % 56;
#pragma unroll
        for (int im = 0; im < 4; ++im) {
#pragma unroll
            for (int r = 0; r < 4; ++r) {
                int oc = m0 + wy * 64 + im * 16 + q * 4 + r;
                float v = acc[im][in][r] + bias[oc];
                v = v > 0.f ? v : 0.f;
                h1[((b * 256 + oc) * 56 + oy) * 56 + ox] = f2bf(v);
            }
        }
    }
}

// ---------------- conv2: R3 exact (proven 272us) ----------------
__global__ __launch_bounds__(256, 3) void conv2_gemm(
    const unsigned short* __restrict__ A2t,  // [2][324][8192] bf16 swizzled tiles
    const unsigned short* __restrict__ h1,   // [32][256][56][56] bf16
    float* __restrict__ c2)                  // [32][256][576] fp32 (pre-zeroed)
{
    __shared__ __align__(16) unsigned short As[2][8192];   // 2 x 16KB
    __shared__ __align__(16) unsigned short BsT[128 * 72]; // tail staging, 18KB
    const int tid = threadIdx.x;
    const int sx = (blockIdx.x & 7) * 18 + (blockIdx.x >> 3);
    const int n0 = sx * 128;
    const int z = blockIdx.z;
    const int lane = tid & 63;
    const int wave = tid >> 6;
    const int wy = wave & 1, wx = wave >> 1;
    const int l16 = lane & 15, q = lane >> 4;

    int boff[4];
#pragma unroll
    for (int in = 0; in < 4; ++in) {
        int n = n0 + wx * 64 + in * 16 + l16;
        int b = n / 576, p = n % 576;
        int oy = p / 24, ox = p % 24;
        boff[in] = b * 802816 + (2 * oy) * 56 + 2 * ox;
    }
    const int tn = tid & 127, thalf = tid >> 7;
    int tbase;
    {
        int ng = n0 + tn;
        int b = ng / 576, p = ng % 576;
        int oy = p / 24, ox = p % 24;
        tbase = b * 802816 + (2 * oy) * 56 + 2 * ox + 8;   // kx = 8
    }

    f32x4 acc[4][4];
#pragma unroll
    for (int im = 0; im < 4; ++im)
#pragma unroll
        for (int in = 0; in < 4; ++in)
            acc[im][in] = (f32x4){0.f, 0.f, 0.f, 0.f};

    const size_t tilebase = (size_t)blockIdx.y * 324 * 8192;

    auto issueA = [&](int c, int buf) {
        const unsigned short* at = A2t + tilebase + (size_t)c * 8192;
        int s0 = wave * 4;
#pragma unroll
        for (int i = 0; i < 4; ++i) {
            int sl = (s0 + i) * 64 + lane;
            gl_lds16(at + sl * 8, &As[buf][sl * 8]);
        }
    };
    auto loadBmain = [&](int c, short8 (&B)[2][4]) {
#pragma unroll
        for (int h = 0; h < 2; ++h) {
            int octk = c * 8 + h * 4 + q;
            int ic = octk / 9;
            int ky = octk - ic * 9;
            int off = ic * 3136 + ky * 56;
#pragma unroll
            for (int in = 0; in < 4; ++in) {
                u32x4u v = *(const u32x4u*)(h1 + boff[in] + off);
                B[h][in] = __builtin_bit_cast(short8, v);
            }
        }
    };
    auto computeChunk = [&](int buf, short8 (&B)[2][4]) {
#pragma unroll
        for (int h = 0; h < 2; ++h) {
            short8 af[4];
#pragma unroll
            for (int im = 0; im < 4; ++im) {
                int row = wy * 64 + im * 16 + l16;
                int koct = h * 4 + q;
                af[im] = *(const short8*)(&As[buf][(row * 8 + (koct ^ (row & 7))) * 8]);
            }
            __builtin_amdgcn_s_setprio(1);
#pragma unroll
            for (int im = 0; im < 4; ++im)
#pragma unroll
                for (int in = 0; in < 4; ++in)
                    acc[im][in] = __builtin_amdgcn_mfma_f32_16x16x32_bf16(
                        af[im], B[h][in], acc[im][in], 0, 0, 0);
            __builtin_amdgcn_s_setprio(0);
        }
    };

    short8 B0[2][4], B1[2][4];

    issueA(z, 0);
    loadBmain(z, B0);
    __asm__ volatile("s_waitcnt vmcnt(8)" ::: "memory");
    __builtin_amdgcn_s_barrier();
    __asm__ volatile("" ::: "memory");

    int c = z;
    for (int it = 0; it < 18; ++it) {
        issueA(c + 8, 1);
        loadBmain(c + 8, B1);
        __asm__ volatile("" ::: "memory");
        computeChunk(0, B0);
        __asm__ volatile("s_waitcnt vmcnt(8)" ::: "memory");
        __builtin_amdgcn_s_barrier();
        __asm__ volatile("" ::: "memory");

        if (it < 17) {
            issueA(c + 16, 0);
            loadBmain(c + 16, B0);
        } else {
            issueA(z + 288, 0);
        }
        __asm__ volatile("" ::: "memory");
        computeChunk(1, B1);
        __asm__ volatile("s_waitcnt vmcnt(8)" ::: "memory");
        __builtin_amdgcn_s_barrier();
        __asm__ volatile("" ::: "memory");
        c += 16;
    }

    int bt = 0;
    for (int ct = z + 288; ct < 324; ct += 8) {
        uint32_t bR[16];
        int base = ct * 64 + thalf * 32 - 18432;
#pragma unroll
        for (int p = 0; p < 16; ++p) {
            int j2 = base + 2 * p;
            int icA = j2 / 9, kyA = j2 - icA * 9;
            int icB = (j2 + 1) / 9, kyB = (j2 + 1) - icB * 9;
            uint32_t ba = h1[tbase + icA * 3136 + kyA * 56];
            uint32_t bb = h1[tbase + icB * 3136 + kyB * 56];
            bR[p] = ba | (bb << 16);
        }
        if (ct + 8 < 324) issueA(ct + 8, bt ^ 1);
        __syncthreads();
#pragma unroll
        for (int p = 0; p < 16; ++p)
            *(uint32_t*)(&BsT[tn * 72 + thalf * 32 + 2 * p]) = bR[p];
        __syncthreads();
#pragma unroll
        for (int h = 0; h < 2; ++h) {
            short8 af[4], bf[4];
#pragma unroll
            for (int im = 0; im < 4; ++im) {
                int row = wy * 64 + im * 16 + l16;
                int koct = h * 4 + q;
                af[im] = *(const short8*)(&As[bt][(row * 8 + (koct ^ (row & 7))) * 8]);
            }
#pragma unroll
            for (int in = 0; in < 4; ++in)
                bf[in] = *(const short8*)(&BsT[(wx * 64 + in * 16 + l16) * 72 + h * 32 + q * 8]);
#pragma unroll
            for (int im = 0; im < 4; ++im)
#pragma unroll
                for (int in = 0; in < 4; ++in)
                    acc[im][in] = __builtin_amdgcn_mfma_f32_16x16x32_bf16(
                        af[im], bf[in], acc[im][in], 0, 0, 0);
        }
        __syncthreads();
        bt ^= 1;
    }

    const int m0 = blockIdx.y * 128;
#pragma unroll
    for (int in = 0; in < 4; ++in) {
        int nn = n0 + wx * 64 + in * 16 + l16;
        int bb = nn / 576, pp = nn % 576;
#pragma unroll
        for (int im = 0; im < 4; ++im) {
#pragma unroll
            for (int r = 0; r < 4; ++r) {
                int oc = m0 + wy * 64 + im * 16 + q * 4 + r;
                atomicAdd(&c2[(bb * 256 + oc) * 576 + pp], acc[im][in][r]);
            }
        }
    }
}

// ---------------- fused squash + iteration-0 capsum (bit-identical to split version) ----------------
__global__ __launch_bounds__(64) void squashG(const float* __restrict__ c2,
                                              const float* __restrict__ bias,
                                              float* __restrict__ caps,
                                              float* __restrict__ G) {
    int r = blockIdx.x, b = blockIdx.y;
    int tid = threadIdx.x;
    const float* cp = c2 + (size_t)(b * 256 + r * 8) * 576;
    float bi[8];
#pragma unroll
    for (int d = 0; d < 8; ++d) bi[d] = bias[r * 8 + d];
    float g[8];
#pragma unroll
    for (int d = 0; d < 8; ++d) g[d] = 0.f;
    for (int jv = 0; jv < 9; ++jv) {
        int p = jv * 64 + tid;
        float s[8]; float n2 = 0.f;
#pragma unroll
        for (int d = 0; d < 8; ++d) {
            s[d] = cp[d * 576 + p] + bi[d];
            n2 += s[d] * s[d];
        }
        float sc = (n2 / (1.f + n2)) / sqrtf(n2 + 1e-8f);
        float* op = caps + ((size_t)((b * 32 + r) * 576 + p)) * 8;
        f32x4 o0 = {sc * s[0], sc * s[1], sc * s[2], sc * s[3]};
        f32x4 o1 = {sc * s[4], sc * s[5], sc * s[6], sc * s[7]};
        ((f32x4*)op)[0] = o0;
        ((f32x4*)op)[1] = o1;
#pragma unroll
        for (int d = 0; d < 8; ++d) g[d] += sc * s[d];
    }
#pragma unroll
    for (int off = 32; off > 0; off >>= 1)
#pragma unroll
        for (int d = 0; d < 8; ++d) g[d] += __shfl_down(g[d], off, 64);
    if (tid == 0) {
        float* gp = G + (size_t)((b * 32 + r) * 10) * 8;
        for (int cc = 0; cc < 10; ++cc)
#pragma unroll
            for (int ii = 0; ii < 8; ++ii) gp[cc * 8 + ii] = g[ii] * 0.1f;
    }
}

// ---------------- routing iterations 1,2 ----------------
__global__ __launch_bounds__(64) void route_accum(const float* __restrict__ caps,
                                                  const float* __restrict__ W,
                                                  const float* __restrict__ V,
                                                  float* __restrict__ G) {
    int r = blockIdx.x, b = blockIdx.y;
    __shared__ float wv[80];
    __shared__ float red[80][64];
    int tid = threadIdx.x;
    for (int v = tid; v < 80; v += 64) {
        int cc = v >> 3, ii = v & 7;
        float s = 0.f;
#pragma unroll
        for (int o = 0; o < 16; ++o)
            s += W[((r * 10 + cc) * 8 + ii) * 16 + o] * V[(b * 10 + cc) * 16 + o];
        wv[v] = s;
    }
    __syncthreads();
    float g[80];
#pragma unroll
    for (int v = 0; v < 80; ++v) g[v] = 0.f;
    const float* cp = caps + (size_t)(b * 32 + r) * 4608;
    for (int j = 0; j < 9; ++j) {
        int p = j * 64 + tid;
        const f32x4* qp = (const f32x4*)(cp + p * 8);
        f32x4 c0 = qp[0], c1 = qp[1];
        float c8[8];
#pragma unroll
        for (int i = 0; i < 4; ++i) { c8[i] = c0[i]; c8[4 + i] = c1[i]; }
        float a[10]; float m = -1e30f;
#pragma unroll
        for (int cc = 0; cc < 10; ++cc) {
            float t = 0.f;
#pragma unroll
            for (int i = 0; i < 8; ++i) t += c8[i] * wv[cc * 8 + i];
            a[cc] = t; m = fmaxf(m, t);
        }
        float sum = 0.f;
#pragma unroll
        for (int cc = 0; cc < 10; ++cc) { a[cc] = __expf(a[cc] - m); sum += a[cc]; }
        float inv = 1.f / sum;
#pragma unroll
        for (int cc = 0; cc < 10; ++cc) {
            float w = a[cc] * inv;
#pragma unroll
            for (int i = 0; i < 8; ++i) g[cc * 8 + i] += w * c8[i];
        }
    }
#pragma unroll
    for (int v = 0; v < 80; ++v) red[v][tid] = g[v];
    __syncthreads();
    for (int v = tid; v < 80; v += 64) {
        float s = 0.f;
        for (int t = 0; t < 64; ++t) s += red[v][t];
        G[(b * 32 + r) * 80 + v] = s;
    }
}

__global__ __launch_bounds__(160) void sv_kernel(const float* __restrict__ G,
                                                 const float* __restrict__ W,
                                                 float* __restrict__ V,
                                                 float* __restrict__ out, int last) {
    int b = blockIdx.x;
    int c = threadIdx.x / 16, o = threadIdx.x % 16;
    __shared__ float sL[10][16];
    float s = 0.f;
    for (int r = 0; r < 32; ++r) {
        const float* g = G + ((b * 32 + r) * 10 + c) * 8;
        const float* w = W + ((r * 10 + c) * 8) * 16 + o;
#pragma unroll
        for (int i = 0; i < 8; ++i) s += g[i] * w[i * 16];
    }
    sL[c][o] = s;
    __syncthreads();
    float n2 = 0.f;
#pragma unroll
    for (int oo = 0; oo < 16; ++oo) { float t = sL[c][oo]; n2 += t * t; }
    float sc = (n2 / (1.f + n2)) / sqrtf(n2 + 1e-8f);
    float v = sc * s;
    V[(b * 10 + c) * 16 + o] += v;
    if (last) out[(b * 10 + c) * 16 + o] = v;
}

// ---------------- launch ----------------
extern "C" void kernel_launch(void* const* d_in, const int* in_sizes, int n_in,
                              void* d_out, int out_size, void* d_ws, size_t ws_size,
                              hipStream_t stream) {
    const float* x  = (const float*)d_in[0];
    const float* w1 = (const float*)d_in[1];
    const float* b1 = (const float*)d_in[2];
    const float* w2 = (const float*)d_in[3];
    const float* b2 = (const float*)d_in[4];
    const float* rw = (const float*)d_in[5];

    char* ws = (char*)d_ws;
    unsigned short* A1   = (unsigned short*)(ws);                  // 262,144 B
    unsigned short* A2   = (unsigned short*)(ws + 262144);         // 10,616,832 B
    unsigned short* h1   = (unsigned short*)(ws + 10878976);       // 51,380,224 B
    float*          c2   = (float*)(ws + 62259200);                // 18,874,368 B
    float*          caps = (float*)(ws + 81133568);                // 18,874,368 B
    float*          V    = (float*)(ws + 100007936);               // 20,480 B
    float*          G    = (float*)(ws + 100028416);               // 327,680 B
    // xb lives inside c2's slot; c2 is memset AFTER conv1 is done with xb
    unsigned short* xb   = (unsigned short*)(ws + 62259200);       // 786,432 B

    hipLaunchKernelGGL(cvt_w1, dim3(256), dim3(256), 0, stream, w1, A1);
    hipLaunchKernelGGL(cvt_xbf, dim3(1536), dim3(256), 0, stream, x, xb);
    hipLaunchKernelGGL(cvt_w2, dim3(20736), dim3(256), 0, stream, w2, A2);
    hipLaunchKernelGGL(conv1_gemm, dim3(784, 2), dim3(256), 0, stream, A1, xb, b1, h1);
    hipMemsetAsync(c2, 0, 18874368, stream);
    hipLaunchKernelGGL(conv2_gemm, dim3(144, 2, 8), dim3(256), 0, stream, A2, h1, c2);
    hipLaunchKernelGGL(squashG, dim3(32, 32), dim3(64), 0, stream, c2, b2, caps, G);
    hipMemsetAsync(V, 0, 5120 * sizeof(float), stream);
    hipLaunchKernelGGL(sv_kernel, dim3(32), dim3(160), 0, stream, G, rw, V, (float*)d_out, 0);
    for (int it = 1; it < 3; ++it) {
        hipLaunchKernelGGL(route_accum, dim3(32, 32), dim3(64), 0, stream, caps, rw, V, G);
        hipLaunchKernelGGL(sv_kernel, dim3(32), dim3(160), 0, stream, G, rw, V,
                           (float*)d_out, it == 2 ? 1 : 0);
    }
}